// Round 11
// baseline (240.314 us; speedup 1.0000x reference)
//
#include <hip/hip_runtime.h>

#define QN 8192
#define CCH 64
#define NROW 65536   // B*Q*4
#define MR 32        // rows per block in k_dot
#define NBLK (NROW / MR)   // 2048
#define H0S 264      // LDS f16 stride for h0/h1 staging
#define UW 784       // u width: 768 outputs (k*256+j) + 3 bias cols + pad
#define SVP 592      // s_val padded stride (f16) in k_u

typedef _Float16 f16x8 __attribute__((ext_vector_type(8)));
typedef _Float16 f16x4 __attribute__((ext_vector_type(4)));
typedef _Float16 f16x2 __attribute__((ext_vector_type(2)));
typedef float f32x4 __attribute__((ext_vector_type(4)));

#if __has_builtin(__builtin_amdgcn_fdot2)
#define FDOT2(A, B, C) __builtin_amdgcn_fdot2((A), (B), (C), false)
#else
#define FDOT2(A, B, C) fmaf((float)(A)[1], (float)(B)[1], fmaf((float)(A)[0], (float)(B)[0], (C)))
#endif
// 8-wide f16 dot via 4x fdot2 — all element indices are LITERALS
#define DOT8(H, U, ACC) do {                                                                      \
    ACC = FDOT2(((f16x2){(H)[0], (H)[1]}), ((f16x2){(U)[0], (U)[1]}), ACC);                       \
    ACC = FDOT2(((f16x2){(H)[2], (H)[3]}), ((f16x2){(U)[2], (U)[3]}), ACC);                       \
    ACC = FDOT2(((f16x2){(H)[4], (H)[5]}), ((f16x2){(U)[4], (U)[5]}), ACC);                       \
    ACC = FDOT2(((f16x2){(H)[6], (H)[7]}), ((f16x2){(U)[6], (U)[7]}), ACC);                       \
} while (0)

__device__ __forceinline__ float gelu_f(float x) {
    float x2 = x * x;
    float tt = fmaf(0.044715f, x2, 1.0f);
    float e = __builtin_amdgcn_exp2f(2.3022081597f * x * tt);
    float r = __builtin_amdgcn_rcpf(1.0f + e);
    return x - x * r;
}

// ---------------- K_pre: conv (0..2177) + prep (2178..2433) + cvt (2434..4453)
// cvt is READ-COALESCED / write-scattered: thread = flat source element; destination
// (tl,kf,ln,jj) computed by the inverse permutation. Scattered 2B writes don't stall;
// the old scattered 4B reads did (one L2 transaction per lane, 6.9KB stride).
__global__ __launch_bounds__(256) void k_pre(const float* __restrict__ inp,
                                             const float* __restrict__ ew,
                                             const float* __restrict__ eb,
                                             const float* __restrict__ coord,
                                             const float* __restrict__ scale,
                                             const float* __restrict__ sw0,
                                             const float* __restrict__ sb0,
                                             const float* __restrict__ sw1,
                                             const float* __restrict__ sb1,
                                             const float* __restrict__ iw1,
                                             const float* __restrict__ iw2,
                                             const float* __restrict__ ib2,
                                             float* __restrict__ featpad,
                                             float4* __restrict__ mlp_in,
                                             int2* __restrict__ ihiw,
                                             float* __restrict__ scoreg,
                                             _Float16* __restrict__ w1tp,
                                             _Float16* __restrict__ w3tp) {
    const int bb = blockIdx.x;
    const int tt0 = threadIdx.x;
    if (bb < 2178) {
        __shared__ float s_ew[1728];
        for (int i = tt0; i < 1728; i += 256) s_ew[i] = ew[i];
        __syncthreads();
        int idx = bb * 256 + tt0;
        const int total = 2 * 66 * 66 * CCH;
        if (idx >= total) return;
        int o = idx & 63; int pix = idx >> 6;
        int xx = pix % 66; int t2 = pix / 66;
        int yy = t2 % 66;  int b = t2 / 66;
        int y = yy - 1, x = xx - 1;
        float acc = 0.0f;
        if (y >= 0 && y < 64 && x >= 0 && x < 64) {
            acc = eb[o];
            for (int i = 0; i < 3; ++i) {
                const float* ip = inp + ((b * 3 + i) * 64) * 64;
                const float* wp = s_ew + (o * 3 + i) * 9;
                #pragma unroll
                for (int ky = 0; ky < 3; ++ky) {
                    int sy = y + ky - 1;
                    if (sy < 0 || sy > 63) continue;
                    #pragma unroll
                    for (int kx = 0; kx < 3; ++kx) {
                        int sx = x + kx - 1;
                        if (sx < 0 || sx > 63) continue;
                        acc += ip[sy * 64 + sx] * wp[ky * 3 + kx];
                    }
                }
            }
        }
        featpad[idx] = acc;
    } else if (bb < 2434) {
        int row = (bb - 2178) * 256 + tt0;
        int v = row & 3;
        int bq = row >> 2;
        int b = bq >> 13;
        float c0 = coord[bq * 2 + 0], c1 = coord[bq * 2 + 1];
        float s0 = scale[bq * 2 + 0], s1 = scale[bq * 2 + 1];
        float s00 = scale[(b * QN) * 2 + 0];
        float s01 = scale[(b * QN) * 2 + 1];
        float rx = (1.0f - s00) / 63.0f;
        float ry = (1.0f - s01) / 63.0f;
        float vx = (v & 2) ? 1.0f : -1.0f;
        float vy = (v & 1) ? 1.0f : -1.0f;
        float cc0 = c0 + vx * rx + 1e-6f;
        float cc1 = c1 + vy * ry + 1e-6f;
        cc0 = fminf(fmaxf(cc0, -1.0f + 1e-6f), 1.0f - 1e-6f);
        cc1 = fminf(fmaxf(cc1, -1.0f + 1e-6f), 1.0f - 1e-6f);
        int ih = (int)rintf((cc0 + 1.0f) * 32.0f - 0.5f);
        int iw = (int)rintf((cc1 + 1.0f) * 32.0f - 0.5f);
        ih = min(max(ih, 0), 63);
        iw = min(max(iw, 0), 63);
        float ck0 = (2.0f * (float)ih + 1.0f) / 64.0f - 1.0f;
        float ck1 = (2.0f * (float)iw + 1.0f) / 64.0f - 1.0f;
        float rel0 = (c0 - ck0) * 64.0f;
        float rel1 = (c1 - ck1) * 64.0f;
        mlp_in[row] = make_float4(rel0, rel1, s0 * 64.0f, s1 * 64.0f);
        ihiw[row] = make_int2(ih, iw);
        float sc = sb1[0];
        #pragma unroll 4
        for (int t2 = 0; t2 < 256; ++t2) {
            float h = gelu_f(fmaf(rel0, sw0[t2], fmaf(rel1, sw0[256 + t2], sb0[t2])));
            sc = fmaf(h, sw1[t2], sc);
        }
        scoreg[row] = sc;
    } else {
        int idx = (bb - 2434) * 256 + tt0;
        if (idx < 442368) {
            // iw2 flat element (coalesced read): j = row, n = col
            float val = iw2[idx];
            int j = idx / 1728, n = idx - j * 1728;
            int k = n % 3, m = n / 3;
            int tap = m % 9, cch = m / 9;
            int o = k * 256 + j;              // w3tp column (0..767)
            int v = tap * 64 + cch;           // contraction index (0..575)
            int tl = o >> 4, kf = v >> 5;
            int ln = (((v & 31) >> 3) << 4) | (o & 15);
            int jj = v & 7;
            w3tp[((tl * 18 + kf) * 64 + ln) * 8 + jj] = (_Float16)val;
        } else if (idx < 451584) {
            // tl=48 section: bias cols (o16<3) + zero pad, forward layout
            int e = idx - 442368;             // [0,9216)
            int jj = e & 7, ln = (e >> 3) & 63, kf = e >> 9;   // kf 0..17
            int o16 = ln & 15;
            int v = kf * 32 + ((ln >> 4) << 3) + jj;
            int tap = v >> 6, cch = v & 63;
            float val = (o16 < 3) ? ib2[(cch * 9 + tap) * 3 + o16] : 0.0f;
            w3tp[((48 * 18 + kf) * 64 + ln) * 8 + jj] = (_Float16)val;
        } else {
            // iw1 flat element (coalesced read): kk = row, col = col
            int f2 = idx - 451584;            // [0,65536)
            float val = iw1[f2];
            int kk = f2 >> 8, col = f2 & 255;
            int ct = col >> 4, kf = kk >> 5;
            int ln = (((kk & 31) >> 3) << 4) | (col & 15);
            int jj = kk & 7;
            w1tp[((ct * 8 + kf) * 64 + ln) * 8 + jj] = (_Float16)val;
        }
    }
}

// ---------------- K_u: per-pixel unfold gather -> u[pix][784] = value(576) @ w3tp
// grid 1024 = 256 pixel-groups x 4 tile-slices; slot=(th<<2)|wave covers tiles
// {slot, slot+16, slot+32(,48)}. 4 blocks/CU (LDS 37.9KB x4 = 151.6KB) vs round-10's 1.
__global__ __launch_bounds__(256, 4) void k_u(const float* __restrict__ featpad,
                                              const _Float16* __restrict__ w3tp,
                                              _Float16* __restrict__ u) {
    __shared__ __align__(16) _Float16 s_val[32 * SVP];   // 37,888 B
    __shared__ int s_dtab[9];
    const int t = threadIdx.x;
    const int wave = t >> 6, lane = t & 63, quad = lane >> 4, l15 = lane & 15;
    const int pg = blockIdx.x & 255;
    const int slotid = ((blockIdx.x >> 8) << 2) | wave;   // 0..15
    if (t < 9) { int dy = t / 3; s_dtab[t] = (dy * 66 + (t - 3 * dy)) * 64; }
    {
        int p = t & 31, half = t >> 5;
        int slot = pg * 32 + p;
        int b = slot >> 12, rem = slot & 4095, y = rem >> 6, x = rem & 63;
        int base = ((b * 66 + y) * 66 + x) * 64;
        __syncthreads();   // s_dtab ready
        #pragma unroll
        for (int i = 0; i < 18; ++i) {
            int v0 = half * 72 + i * 4;
            int tap = v0 >> 6, cch = v0 & 63;
            float4 f = *(const float4*)(featpad + base + s_dtab[tap] + cch);
            f16x4 hv = {(_Float16)f.x, (_Float16)f.y, (_Float16)f.z, (_Float16)f.w};
            *(f16x4*)(s_val + p * SVP + v0) = hv;
        }
    }
    __syncthreads();

    #pragma unroll 1
    for (int tl = slotid; tl < 49; tl += 16) {
        const _Float16* wp = w3tp + ((size_t)(tl * 18) * 64 + lane) * 8;
        f16x8 bbuf[18];
        #pragma unroll
        for (int kf = 0; kf < 18; ++kf) bbuf[kf] = *(const f16x8*)(wp + (size_t)kf * 512);
        f32x4 ac0 = {0.f, 0.f, 0.f, 0.f}, ac1 = {0.f, 0.f, 0.f, 0.f};
        #pragma unroll
        for (int kf = 0; kf < 18; ++kf) {
            f16x8 a0 = *(const f16x8*)(s_val + l15 * SVP + kf * 32 + quad * 8);
            f16x8 a1 = *(const f16x8*)(s_val + (16 + l15) * SVP + kf * 32 + quad * 8);
            ac0 = __builtin_amdgcn_mfma_f32_16x16x32_f16(a0, bbuf[kf], ac0, 0, 0, 0);
            ac1 = __builtin_amdgcn_mfma_f32_16x16x32_f16(a1, bbuf[kf], ac1, 0, 0, 0);
        }
        size_t pb = (size_t)(pg * 32 + quad * 4) * UW + tl * 16 + l15;
        #pragma unroll
        for (int rg = 0; rg < 4; ++rg) u[pb + (size_t)rg * UW] = (_Float16)ac0[rg];
        pb += (size_t)16 * UW;
        #pragma unroll
        for (int rg = 0; rg < 4; ++rg) u[pb + (size_t)rg * UW] = (_Float16)ac1[rg];
    }
}

// ---- macros for k_dot h1 pipeline (MR=32: 2 row-tiles)
#define LDX1(B, CT) do { const _Float16* wp_ = w1tp + (size_t)((CT) * 8) * 512 + lane * 8;        \
    _Pragma("unroll") for (int kf_ = 0; kf_ < 4; ++kf_) B[kf_] = *(const f16x8*)(wp_ + kf_ * 512); } while (0)
#define LDY1(B, CT) do { const _Float16* wp_ = w1tp + (size_t)((CT) * 8 + 4) * 512 + lane * 8;    \
    _Pragma("unroll") for (int kf_ = 0; kf_ < 4; ++kf_) B[kf_] = *(const f16x8*)(wp_ + kf_ * 512); } while (0)
#define ZACCB(BV) do { _Pragma("unroll") for (int rt_ = 0; rt_ < 2; ++rt_)                        \
    acc[rt_] = (f32x4){(BV), (BV), (BV), (BV)}; } while (0)
#define MFMAH(B, OFS) do { _Pragma("unroll") for (int kf_ = 0; kf_ < 4; ++kf_)                    \
    { _Pragma("unroll") for (int rt_ = 0; rt_ < 2; ++rt_)                                         \
      acc[rt_] = __builtin_amdgcn_mfma_f32_16x16x32_f16(a[rt_][kf_ + (OFS)], B[kf_], acc[rt_], 0, 0, 0); } } while (0)
#define H1EPI(CT) do { int col_ = (CT) * 16 + l15;                                                \
    _Pragma("unroll") for (int rt_ = 0; rt_ < 2; ++rt_)                                           \
      { _Pragma("unroll") for (int rg_ = 0; rg_ < 4; ++rg_)                                       \
        s_h0[(rt_ * 16 + quad * 4 + rg_) * H0S + col_] = (_Float16)gelu_f(acc[rt_][rg_]); } } while (0)

// ---------------- K_dot: h0 -> h1 (MFMA) -> per-row dot with u[slot] -> +score -> weight MLP
// launch_bounds (256,3): 170-reg cap fits the ~150-reg h1 pipeline with ZERO spill
// ((256,4)'s 128-reg cap spilled ~66 MB/dispatch each way — round 9).
__global__ __launch_bounds__(256, 3) void k_dot(const float4* __restrict__ mlp_in,
                                                const int2* __restrict__ ihiw,
                                                const float* __restrict__ iw0,
                                                const float* __restrict__ ib0,
                                                const _Float16* __restrict__ w1tp,
                                                const float* __restrict__ ib1,
                                                const _Float16* __restrict__ ubuf,
                                                const float* __restrict__ scoreg,
                                                const float* __restrict__ ww0,
                                                const float* __restrict__ wb0,
                                                const float* __restrict__ ww1,
                                                const float* __restrict__ wb1,
                                                float* __restrict__ out) {
    __shared__ __align__(16) _Float16 s_h0[MR * H0S];   // 16,896 B
    __shared__ float4 s_min[MR];
    __shared__ int    s_slot[MR];
    __shared__ float  s_pred[MR][3];
    __shared__ float  s_score[MR];
    __shared__ float  s_dred[MR][3][8];
    __shared__ float  s_wred[24][4];

    const int t = threadIdx.x;
    const int wave = t >> 6, lane = t & 63, quad = lane >> 4, l15 = lane & 15;
    const int rowbase = blockIdx.x * MR;

    if (t < MR) {
        int row = rowbase + t;
        s_min[t] = mlp_in[row];
        s_score[t] = scoreg[row];
        int b = row >> 15;
        int2 p = ihiw[row];
        s_slot[t] = (b << 12) + (p.x << 6) + p.y;
    }
    __syncthreads();

    // ---- h0 (4->256) fp32 VALU -> LDS f16 ([32][264])
    {
        float w0 = iw0[t], w1 = iw0[256 + t], w2 = iw0[512 + t], w3 = iw0[768 + t];
        float bb = ib0[t];
        #pragma unroll 4
        for (int r = 0; r < MR; ++r) {
            float4 m = s_min[r];
            s_h0[r * H0S + t] =
                (_Float16)gelu_f(fmaf(m.x, w0, fmaf(m.y, w1, fmaf(m.z, w2, fmaf(m.w, w3, bb)))));
        }
    }
    __syncthreads();

    const int w4 = wave * 4;
    const float bibA = ib1[(w4 + 0) * 16 + l15];
    const float bibB = ib1[(w4 + 1) * 16 + l15];
    const float bibC = ib1[(w4 + 2) * 16 + l15];
    const float bibD = ib1[(w4 + 3) * 16 + l15];

    f16x8 bX0[4], bX1[4], bY0[4], bY1[4];
    f32x4 acc[2];

    LDX1(bX0, w4);
    LDY1(bY0, w4);
    LDX1(bX1, w4 + 1);

    f16x8 a[2][8];
    #pragma unroll
    for (int rt = 0; rt < 2; ++rt)
        #pragma unroll
        for (int kf = 0; kf < 8; ++kf)
            a[rt][kf] = *(const f16x8*)(s_h0 + (rt * 16 + l15) * H0S + kf * 32 + quad * 8);
    __syncthreads();   // all h0 reads done before in-place h1 writes

    // ---- h1 (256->256) MFMA, pipelined
    LDY1(bY1, w4 + 1);
    ZACCB(bibA); MFMAH(bX0, 0);
    LDX1(bX0, w4 + 2);
    MFMAH(bY0, 4);
    H1EPI(w4);
    LDY1(bY0, w4 + 2);
    ZACCB(bibB); MFMAH(bX1, 0);
    LDX1(bX1, w4 + 3);
    MFMAH(bY1, 4);
    H1EPI(w4 + 1);
    LDY1(bY1, w4 + 3);
    ZACCB(bibC); MFMAH(bX0, 0);
    MFMAH(bY0, 4);
    H1EPI(w4 + 2);
    ZACCB(bibD); MFMAH(bX1, 0);
    MFMAH(bY1, 4);
    H1EPI(w4 + 3);
    __syncthreads();   // h1 in s_h0

    // ---- per-row dot: pred_k = sum_j h1[r][j] * u[slot][k*256+j]   (8 threads/row, fdot2)
    {
        int r = t >> 3, sub = t & 7;
        int j0 = sub * 32;
        const _Float16* hb = s_h0 + r * H0S + j0;
        const _Float16* ub = ubuf + (size_t)s_slot[r] * UW + j0;
        float a0 = 0.f, a1 = 0.f, a2 = 0.f;
        #pragma unroll
        for (int c = 0; c < 4; ++c) {
            f16x8 h8 = *(const f16x8*)(hb + c * 8);
            f16x8 u0 = *(const f16x8*)(ub + c * 8);
            f16x8 u1 = *(const f16x8*)(ub + 256 + c * 8);
            f16x8 u2 = *(const f16x8*)(ub + 512 + c * 8);
            DOT8(h8, u0, a0);
            DOT8(h8, u1, a1);
            DOT8(h8, u2, a2);
        }
        s_dred[r][0][sub] = a0;
        s_dred[r][1][sub] = a1;
        s_dred[r][2][sub] = a2;
    }
    __syncthreads();
    if (t < 96) {
        int r = t / 3, k = t - 3 * r;
        float s = (float)ubuf[(size_t)s_slot[r] * UW + 768 + k];
        #pragma unroll
        for (int q = 0; q < 8; ++q) s += s_dred[r][k][q];
        s_pred[r][k] = s;
    }
    __syncthreads();

    // ---- fused weight MLP (4->256->1): 8 bq x 3 k outputs, 4 sub-threads each
    if (t < 96) {
        int o = t >> 2, sub = t & 3;
        int bql = o / 3, k = o - 3 * bql;
        float x0 = s_pred[bql * 4 + 0][k] + s_score[bql * 4 + 0];
        float x1 = s_pred[bql * 4 + 1][k] + s_score[bql * 4 + 1];
        float x2 = s_pred[bql * 4 + 2][k] + s_score[bql * 4 + 2];
        float x3 = s_pred[bql * 4 + 3][k] + s_score[bql * 4 + 3];
        float acc2 = 0.0f;
        int j0 = sub * 64;
        #pragma unroll 4
        for (int j = j0; j < j0 + 64; ++j) {
            float h = gelu_f(fmaf(x0, ww0[j], fmaf(x1, ww0[256 + j],
                          fmaf(x2, ww0[512 + j], fmaf(x3, ww0[768 + j], wb0[j])))));
            acc2 = fmaf(h, ww1[j], acc2);
        }
        s_wred[o][sub] = acc2;
    }
    __syncthreads();
    if (t < 24) {
        int bql = t / 3, k = t - 3 * bql;
        float r2 = s_wred[t][0] + s_wred[t][1] + s_wred[t][2] + s_wred[t][3] + wb1[0];
        out[(blockIdx.x * 8 + bql) * 3 + k] = r2;
    }
}

extern "C" void kernel_launch(void* const* d_in, const int* in_sizes, int n_in,
                              void* d_out, int out_size, void* d_ws, size_t ws_size,
                              hipStream_t stream) {
    const float* inp   = (const float*)d_in[0];
    const float* coord = (const float*)d_in[1];
    const float* scale = (const float*)d_in[2];
    const float* ew    = (const float*)d_in[3];
    const float* eb    = (const float*)d_in[4];
    const float* iw0   = (const float*)d_in[5];
    const float* ib0   = (const float*)d_in[6];
    const float* iw1   = (const float*)d_in[7];
    const float* ib1   = (const float*)d_in[8];
    const float* iw2   = (const float*)d_in[9];
    const float* ib2   = (const float*)d_in[10];
    const float* sw0   = (const float*)d_in[11];
    const float* sb0   = (const float*)d_in[12];
    const float* sw1   = (const float*)d_in[13];
    const float* sb1   = (const float*)d_in[14];
    const float* ww0   = (const float*)d_in[15];
    const float* wb0   = (const float*)d_in[16];
    const float* ww1   = (const float*)d_in[17];
    const float* wb1   = (const float*)d_in[18];
    float* out = (float*)d_out;

    char* ws = (char*)d_ws;
    float*     featpad = (float*)(ws + 0);           //  2,230,272
    float4*    mlp_in  = (float4*)(ws + 2230272);    //  1,048,576
    int2*      ihiw    = (int2*)(ws + 3278848);      //    524,288
    float*     scoreg  = (float*)(ws + 3803136);     //    262,144
    _Float16*  w1tp    = (_Float16*)(ws + 4065280);  //    131,072
    _Float16*  w3tp    = (_Float16*)(ws + 4196352);  //    903,168
    _Float16*  u       = (_Float16*)(ws + 5099520);  // 12,845,056  (end 17,944,576)

    k_pre<<<dim3(4454), dim3(256), 0, stream>>>(inp, ew, eb, coord, scale,
                                                sw0, sb0, sw1, sb1, iw1, iw2, ib2,
                                                featpad, mlp_in, ihiw, scoreg,
                                                w1tp, w3tp);
    k_u<<<dim3(1024), dim3(256), 0, stream>>>(featpad, w3tp, u);
    k_dot<<<dim3(NBLK), dim3(256), 0, stream>>>(mlp_in, ihiw, iw0, ib0, w1tp, ib1,
                                                u, scoreg, ww0, wb0, ww1, wb1, out);
}

// Round 12
// 223.588 us; speedup vs baseline: 1.0748x; 1.0748x over previous
//
#include <hip/hip_runtime.h>

#define QN 8192
#define CCH 64
#define NROW 65536   // B*Q*4
#define MR 32        // rows per block in k_dot
#define NBLK (NROW / MR)   // 2048
#define H0S 264      // LDS f16 stride for h0/h1 staging
#define UW 784       // u width: 768 outputs (k*256+j) + 3 bias cols + pad
#define SVP 592      // s_val padded stride (f16) in k_u

typedef _Float16 f16x8 __attribute__((ext_vector_type(8)));
typedef _Float16 f16x4 __attribute__((ext_vector_type(4)));
typedef _Float16 f16x2 __attribute__((ext_vector_type(2)));
typedef float f32x4 __attribute__((ext_vector_type(4)));

#if __has_builtin(__builtin_amdgcn_fdot2)
#define FDOT2(A, B, C) __builtin_amdgcn_fdot2((A), (B), (C), false)
#else
#define FDOT2(A, B, C) fmaf((float)(A)[1], (float)(B)[1], fmaf((float)(A)[0], (float)(B)[0], (C)))
#endif
// 8-wide f16 dot via 4x fdot2 — all element indices are LITERALS
#define DOT8(H, U, ACC) do {                                                                      \
    ACC = FDOT2(((f16x2){(H)[0], (H)[1]}), ((f16x2){(U)[0], (U)[1]}), ACC);                       \
    ACC = FDOT2(((f16x2){(H)[2], (H)[3]}), ((f16x2){(U)[2], (U)[3]}), ACC);                       \
    ACC = FDOT2(((f16x2){(H)[4], (H)[5]}), ((f16x2){(U)[4], (U)[5]}), ACC);                       \
    ACC = FDOT2(((f16x2){(H)[6], (H)[7]}), ((f16x2){(U)[6], (U)[7]}), ACC);                       \
} while (0)

__device__ __forceinline__ float gelu_f(float x) {
    float x2 = x * x;
    float tt = fmaf(0.044715f, x2, 1.0f);
    float e = __builtin_amdgcn_exp2f(2.3022081597f * x * tt);
    float r = __builtin_amdgcn_rcpf(1.0f + e);
    return x - x * r;
}

// ---------------- K_pre: conv (0..2177) + prep (2178..2433) + cvt w3tp/w1tp (2434..4453)
__global__ __launch_bounds__(256) void k_pre(const float* __restrict__ inp,
                                             const float* __restrict__ ew,
                                             const float* __restrict__ eb,
                                             const float* __restrict__ coord,
                                             const float* __restrict__ scale,
                                             const float* __restrict__ sw0,
                                             const float* __restrict__ sb0,
                                             const float* __restrict__ sw1,
                                             const float* __restrict__ sb1,
                                             const float* __restrict__ iw1,
                                             const float* __restrict__ iw2,
                                             const float* __restrict__ ib2,
                                             float* __restrict__ featpad,
                                             float4* __restrict__ mlp_in,
                                             int2* __restrict__ ihiw,
                                             float* __restrict__ scoreg,
                                             _Float16* __restrict__ w1tp,
                                             _Float16* __restrict__ w3tp) {
    const int bb = blockIdx.x;
    const int tt0 = threadIdx.x;
    if (bb < 2178) {
        __shared__ float s_ew[1728];
        for (int i = tt0; i < 1728; i += 256) s_ew[i] = ew[i];
        __syncthreads();
        int idx = bb * 256 + tt0;
        const int total = 2 * 66 * 66 * CCH;
        if (idx >= total) return;
        int o = idx & 63; int pix = idx >> 6;
        int xx = pix % 66; int t2 = pix / 66;
        int yy = t2 % 66;  int b = t2 / 66;
        int y = yy - 1, x = xx - 1;
        float acc = 0.0f;
        if (y >= 0 && y < 64 && x >= 0 && x < 64) {
            acc = eb[o];
            for (int i = 0; i < 3; ++i) {
                const float* ip = inp + ((b * 3 + i) * 64) * 64;
                const float* wp = s_ew + (o * 3 + i) * 9;
                #pragma unroll
                for (int ky = 0; ky < 3; ++ky) {
                    int sy = y + ky - 1;
                    if (sy < 0 || sy > 63) continue;
                    #pragma unroll
                    for (int kx = 0; kx < 3; ++kx) {
                        int sx = x + kx - 1;
                        if (sx < 0 || sx > 63) continue;
                        acc += ip[sy * 64 + sx] * wp[ky * 3 + kx];
                    }
                }
            }
        }
        featpad[idx] = acc;
    } else if (bb < 2434) {
        int row = (bb - 2178) * 256 + tt0;
        int v = row & 3;
        int bq = row >> 2;
        int b = bq >> 13;
        float c0 = coord[bq * 2 + 0], c1 = coord[bq * 2 + 1];
        float s0 = scale[bq * 2 + 0], s1 = scale[bq * 2 + 1];
        float s00 = scale[(b * QN) * 2 + 0];
        float s01 = scale[(b * QN) * 2 + 1];
        float rx = (1.0f - s00) / 63.0f;
        float ry = (1.0f - s01) / 63.0f;
        float vx = (v & 2) ? 1.0f : -1.0f;
        float vy = (v & 1) ? 1.0f : -1.0f;
        float cc0 = c0 + vx * rx + 1e-6f;
        float cc1 = c1 + vy * ry + 1e-6f;
        cc0 = fminf(fmaxf(cc0, -1.0f + 1e-6f), 1.0f - 1e-6f);
        cc1 = fminf(fmaxf(cc1, -1.0f + 1e-6f), 1.0f - 1e-6f);
        int ih = (int)rintf((cc0 + 1.0f) * 32.0f - 0.5f);
        int iw = (int)rintf((cc1 + 1.0f) * 32.0f - 0.5f);
        ih = min(max(ih, 0), 63);
        iw = min(max(iw, 0), 63);
        float ck0 = (2.0f * (float)ih + 1.0f) / 64.0f - 1.0f;
        float ck1 = (2.0f * (float)iw + 1.0f) / 64.0f - 1.0f;
        float rel0 = (c0 - ck0) * 64.0f;
        float rel1 = (c1 - ck1) * 64.0f;
        mlp_in[row] = make_float4(rel0, rel1, s0 * 64.0f, s1 * 64.0f);
        ihiw[row] = make_int2(ih, iw);
        float sc = sb1[0];
        #pragma unroll 4
        for (int t2 = 0; t2 < 256; ++t2) {
            float h = gelu_f(fmaf(rel0, sw0[t2], fmaf(rel1, sw0[256 + t2], sb0[t2])));
            sc = fmaf(h, sw1[t2], sc);
        }
        scoreg[row] = sc;
    } else {
        // convert weights to LANE-MAJOR fragment layouts.
        int idx = (bb - 2434) * 256 + tt0;
        if (idx < 451584) {
            int jj = idx & 7, ln = (idx >> 3) & 63;
            int tlkf = idx >> 9;
            int tl = tlkf / 18, kf = tlkf - tl * 18;
            int o = tl * 16 + (ln & 15);
            int v = kf * 32 + (ln >> 4) * 8 + jj;
            int tap = v >> 6, cch = v & 63;
            float val = 0.0f;
            if (o < 768) {
                int j = o & 255, k = o >> 8;
                val = iw2[j * 1728 + (cch * 9 + tap) * 3 + k];
            } else if (o < 771) {
                val = ib2[(cch * 9 + tap) * 3 + (o - 768)];
            }
            w3tp[idx] = (_Float16)val;
        } else {
            int i2 = idx - 451584;
            int j = i2 & 7, ln = (i2 >> 3) & 63, kf = (i2 >> 9) & 7, ct = i2 >> 12;
            int col = ct * 16 + (ln & 15);
            int kk = kf * 32 + (ln >> 4) * 8 + j;
            w1tp[i2] = (_Float16)iw1[kk * 256 + col];
        }
    }
}

// ---------------- K_u: per-pixel unfold gather -> u[pix][784] = value(576) @ w3tp
__global__ __launch_bounds__(256) void k_u(const float* __restrict__ featpad,
                                           const _Float16* __restrict__ w3tp,
                                           _Float16* __restrict__ u) {
    __shared__ __align__(16) _Float16 s_val[32 * SVP];   // 37,888 B
    __shared__ int s_dtab[9];
    const int t = threadIdx.x;
    const int wave = t >> 6, lane = t & 63, quad = lane >> 4, l15 = lane & 15;
    if (t < 9) { int dy = t / 3; s_dtab[t] = (dy * 66 + (t - 3 * dy)) * 64; }
    {
        int p = t & 31, half = t >> 5;
        int slot = blockIdx.x * 32 + p;
        int b = slot >> 12, rem = slot & 4095, y = rem >> 6, x = rem & 63;
        int base = ((b * 66 + y) * 66 + x) * 64;
        __syncthreads();   // s_dtab ready
        #pragma unroll
        for (int i = 0; i < 18; ++i) {
            int v0 = half * 72 + i * 4;
            int tap = v0 >> 6, cch = v0 & 63;
            float4 f = *(const float4*)(featpad + base + s_dtab[tap] + cch);
            f16x4 hv = {(_Float16)f.x, (_Float16)f.y, (_Float16)f.z, (_Float16)f.w};
            *(f16x4*)(s_val + p * SVP + v0) = hv;
        }
    }
    __syncthreads();

    const int t0 = (wave == 0) ? 0 : 1 + wave * 12;   // 0,13,25,37
    const int nt = (wave == 0) ? 13 : 12;
    #pragma unroll 1
    for (int tt = 0; tt < nt; ++tt) {
        int tl = t0 + tt;
        const _Float16* wp = w3tp + ((size_t)(tl * 18) * 64 + lane) * 8;
        f16x8 bbuf[18];
        #pragma unroll
        for (int kf = 0; kf < 18; ++kf) bbuf[kf] = *(const f16x8*)(wp + (size_t)kf * 512);
        f32x4 ac0 = {0.f, 0.f, 0.f, 0.f}, ac1 = {0.f, 0.f, 0.f, 0.f};
        #pragma unroll
        for (int kf = 0; kf < 18; ++kf) {
            f16x8 a0 = *(const f16x8*)(s_val + l15 * SVP + kf * 32 + quad * 8);
            f16x8 a1 = *(const f16x8*)(s_val + (16 + l15) * SVP + kf * 32 + quad * 8);
            ac0 = __builtin_amdgcn_mfma_f32_16x16x32_f16(a0, bbuf[kf], ac0, 0, 0, 0);
            ac1 = __builtin_amdgcn_mfma_f32_16x16x32_f16(a1, bbuf[kf], ac1, 0, 0, 0);
        }
        size_t pb = (size_t)(blockIdx.x * 32 + quad * 4) * UW + tl * 16 + l15;
        #pragma unroll
        for (int rg = 0; rg < 4; ++rg) u[pb + (size_t)rg * UW] = (_Float16)ac0[rg];
        pb += (size_t)16 * UW;
        #pragma unroll
        for (int rg = 0; rg < 4; ++rg) u[pb + (size_t)rg * UW] = (_Float16)ac1[rg];
    }
}

// ---- macros for k_dot h1 pipeline (MR=32: 2 row-tiles)
#define LDX1(B, CT) do { const _Float16* wp_ = w1tp + (size_t)((CT) * 8) * 512 + lane * 8;        \
    _Pragma("unroll") for (int kf_ = 0; kf_ < 4; ++kf_) B[kf_] = *(const f16x8*)(wp_ + kf_ * 512); } while (0)
#define LDY1(B, CT) do { const _Float16* wp_ = w1tp + (size_t)((CT) * 8 + 4) * 512 + lane * 8;    \
    _Pragma("unroll") for (int kf_ = 0; kf_ < 4; ++kf_) B[kf_] = *(const f16x8*)(wp_ + kf_ * 512); } while (0)
#define ZACCB(BV) do { _Pragma("unroll") for (int rt_ = 0; rt_ < 2; ++rt_)                        \
    acc[rt_] = (f32x4){(BV), (BV), (BV), (BV)}; } while (0)
#define MFMAH(B, OFS) do { _Pragma("unroll") for (int kf_ = 0; kf_ < 4; ++kf_)                    \
    { _Pragma("unroll") for (int rt_ = 0; rt_ < 2; ++rt_)                                         \
      acc[rt_] = __builtin_amdgcn_mfma_f32_16x16x32_f16(a[rt_][kf_ + (OFS)], B[kf_], acc[rt_], 0, 0, 0); } } while (0)
#define H1EPI(CT) do { int col_ = (CT) * 16 + l15;                                                \
    _Pragma("unroll") for (int rt_ = 0; rt_ < 2; ++rt_)                                           \
      { _Pragma("unroll") for (int rg_ = 0; rg_ < 4; ++rg_)                                       \
        s_h0[(rt_ * 16 + quad * 4 + rg_) * H0S + col_] = (_Float16)gelu_f(acc[rt_][rg_]); } } while (0)

// ---------------- K_dot: h0 -> h1 (MFMA) -> per-row dot with u[slot] -> +score -> weight MLP
// launch_bounds (256,3): 170-reg cap fits the ~150-reg h1 pipeline with ZERO spill
// ((256,4)'s 128-reg cap spilled ~66 MB/dispatch each way — round 9).
__global__ __launch_bounds__(256, 3) void k_dot(const float4* __restrict__ mlp_in,
                                                const int2* __restrict__ ihiw,
                                                const float* __restrict__ iw0,
                                                const float* __restrict__ ib0,
                                                const _Float16* __restrict__ w1tp,
                                                const float* __restrict__ ib1,
                                                const _Float16* __restrict__ ubuf,
                                                const float* __restrict__ scoreg,
                                                const float* __restrict__ ww0,
                                                const float* __restrict__ wb0,
                                                const float* __restrict__ ww1,
                                                const float* __restrict__ wb1,
                                                float* __restrict__ out) {
    __shared__ __align__(16) _Float16 s_h0[MR * H0S];   // 16,896 B
    __shared__ float4 s_min[MR];
    __shared__ int    s_slot[MR];
    __shared__ float  s_pred[MR][3];
    __shared__ float  s_score[MR];
    __shared__ float  s_dred[MR][3][8];
    __shared__ float  s_wred[24][4];

    const int t = threadIdx.x;
    const int wave = t >> 6, lane = t & 63, quad = lane >> 4, l15 = lane & 15;
    const int rowbase = blockIdx.x * MR;

    if (t < MR) {
        int row = rowbase + t;
        s_min[t] = mlp_in[row];
        s_score[t] = scoreg[row];
        int b = row >> 15;
        int2 p = ihiw[row];
        s_slot[t] = (b << 12) + (p.x << 6) + p.y;
    }
    __syncthreads();

    // ---- h0 (4->256) fp32 VALU -> LDS f16 ([32][264])
    {
        float w0 = iw0[t], w1 = iw0[256 + t], w2 = iw0[512 + t], w3 = iw0[768 + t];
        float bb = ib0[t];
        #pragma unroll 4
        for (int r = 0; r < MR; ++r) {
            float4 m = s_min[r];
            s_h0[r * H0S + t] =
                (_Float16)gelu_f(fmaf(m.x, w0, fmaf(m.y, w1, fmaf(m.z, w2, fmaf(m.w, w3, bb)))));
        }
    }
    __syncthreads();

    const int w4 = wave * 4;
    const float bibA = ib1[(w4 + 0) * 16 + l15];
    const float bibB = ib1[(w4 + 1) * 16 + l15];
    const float bibC = ib1[(w4 + 2) * 16 + l15];
    const float bibD = ib1[(w4 + 3) * 16 + l15];

    f16x8 bX0[4], bX1[4], bY0[4], bY1[4];
    f32x4 acc[2];

    LDX1(bX0, w4);
    LDY1(bY0, w4);
    LDX1(bX1, w4 + 1);

    f16x8 a[2][8];
    #pragma unroll
    for (int rt = 0; rt < 2; ++rt)
        #pragma unroll
        for (int kf = 0; kf < 8; ++kf)
            a[rt][kf] = *(const f16x8*)(s_h0 + (rt * 16 + l15) * H0S + kf * 32 + quad * 8);
    __syncthreads();   // all h0 reads done before in-place h1 writes

    // ---- h1 (256->256) MFMA, pipelined
    LDY1(bY1, w4 + 1);
    ZACCB(bibA); MFMAH(bX0, 0);
    LDX1(bX0, w4 + 2);
    MFMAH(bY0, 4);
    H1EPI(w4);
    LDY1(bY0, w4 + 2);
    ZACCB(bibB); MFMAH(bX1, 0);
    LDX1(bX1, w4 + 3);
    MFMAH(bY1, 4);
    H1EPI(w4 + 1);
    LDY1(bY1, w4 + 3);
    ZACCB(bibC); MFMAH(bX0, 0);
    MFMAH(bY0, 4);
    H1EPI(w4 + 2);
    ZACCB(bibD); MFMAH(bX1, 0);
    MFMAH(bY1, 4);
    H1EPI(w4 + 3);
    __syncthreads();   // h1 in s_h0

    // ---- per-row dot: pred_k = sum_j h1[r][j] * u[slot][k*256+j]   (8 threads/row, fdot2)
    {
        int r = t >> 3, sub = t & 7;
        int j0 = sub * 32;
        const _Float16* hb = s_h0 + r * H0S + j0;
        const _Float16* ub = ubuf + (size_t)s_slot[r] * UW + j0;
        float a0 = 0.f, a1 = 0.f, a2 = 0.f;
        #pragma unroll
        for (int c = 0; c < 4; ++c) {
            f16x8 h8 = *(const f16x8*)(hb + c * 8);
            f16x8 u0 = *(const f16x8*)(ub + c * 8);
            f16x8 u1 = *(const f16x8*)(ub + 256 + c * 8);
            f16x8 u2 = *(const f16x8*)(ub + 512 + c * 8);
            DOT8(h8, u0, a0);
            DOT8(h8, u1, a1);
            DOT8(h8, u2, a2);
        }
        s_dred[r][0][sub] = a0;
        s_dred[r][1][sub] = a1;
        s_dred[r][2][sub] = a2;
    }
    __syncthreads();
    if (t < 96) {
        int r = t / 3, k = t - 3 * r;
        float s = (float)ubuf[(size_t)s_slot[r] * UW + 768 + k];
        #pragma unroll
        for (int q = 0; q < 8; ++q) s += s_dred[r][k][q];
        s_pred[r][k] = s;
    }
    __syncthreads();

    // ---- fused weight MLP (4->256->1): 8 bq x 3 k outputs, 4 sub-threads each
    if (t < 96) {
        int o = t >> 2, sub = t & 3;
        int bql = o / 3, k = o - 3 * bql;
        float x0 = s_pred[bql * 4 + 0][k] + s_score[bql * 4 + 0];
        float x1 = s_pred[bql * 4 + 1][k] + s_score[bql * 4 + 1];
        float x2 = s_pred[bql * 4 + 2][k] + s_score[bql * 4 + 2];
        float x3 = s_pred[bql * 4 + 3][k] + s_score[bql * 4 + 3];
        float acc2 = 0.0f;
        int j0 = sub * 64;
        #pragma unroll 4
        for (int j = j0; j < j0 + 64; ++j) {
            float h = gelu_f(fmaf(x0, ww0[j], fmaf(x1, ww0[256 + j],
                          fmaf(x2, ww0[512 + j], fmaf(x3, ww0[768 + j], wb0[j])))));
            acc2 = fmaf(h, ww1[j], acc2);
        }
        s_wred[o][sub] = acc2;
    }
    __syncthreads();
    if (t < 24) {
        int bql = t / 3, k = t - 3 * bql;
        float r2 = s_wred[t][0] + s_wred[t][1] + s_wred[t][2] + s_wred[t][3] + wb1[0];
        out[(blockIdx.x * 8 + bql) * 3 + k] = r2;
    }
}

extern "C" void kernel_launch(void* const* d_in, const int* in_sizes, int n_in,
                              void* d_out, int out_size, void* d_ws, size_t ws_size,
                              hipStream_t stream) {
    const float* inp   = (const float*)d_in[0];
    const float* coord = (const float*)d_in[1];
    const float* scale = (const float*)d_in[2];
    const float* ew    = (const float*)d_in[3];
    const float* eb    = (const float*)d_in[4];
    const float* iw0   = (const float*)d_in[5];
    const float* ib0   = (const float*)d_in[6];
    const float* iw1   = (const float*)d_in[7];
    const float* ib1   = (const float*)d_in[8];
    const float* iw2   = (const float*)d_in[9];
    const float* ib2   = (const float*)d_in[10];
    const float* sw0   = (const float*)d_in[11];
    const float* sb0   = (const float*)d_in[12];
    const float* sw1   = (const float*)d_in[13];
    const float* sb1   = (const float*)d_in[14];
    const float* ww0   = (const float*)d_in[15];
    const float* wb0   = (const float*)d_in[16];
    const float* ww1   = (const float*)d_in[17];
    const float* wb1   = (const float*)d_in[18];
    float* out = (float*)d_out;

    char* ws = (char*)d_ws;
    float*     featpad = (float*)(ws + 0);           //  2,230,272
    float4*    mlp_in  = (float4*)(ws + 2230272);    //  1,048,576
    int2*      ihiw    = (int2*)(ws + 3278848);      //    524,288
    float*     scoreg  = (float*)(ws + 3803136);     //    262,144
    _Float16*  w1tp    = (_Float16*)(ws + 4065280);  //    131,072
    _Float16*  w3tp    = (_Float16*)(ws + 4196352);  //    903,168
    _Float16*  u       = (_Float16*)(ws + 5099520);  // 12,845,056  (end 17,944,576)

    k_pre<<<dim3(4454), dim3(256), 0, stream>>>(inp, ew, eb, coord, scale,
                                                sw0, sb0, sw1, sb1, iw1, iw2, ib2,
                                                featpad, mlp_in, ihiw, scoreg,
                                                w1tp, w3tp);
    k_u<<<dim3(256), dim3(256), 0, stream>>>(featpad, w3tp, u);
    k_dot<<<dim3(NBLK), dim3(256), 0, stream>>>(mlp_in, ihiw, iw0, ib0, w1tp, ib1,
                                                u, scoreg, ww0, wb0, ww1, wb1, out);
}